// Round 3
// baseline (245.447 us; speedup 1.0000x reference)
//
#include <hip/hip_runtime.h>
#include <hip/hip_bf16.h>

// Problem constants (from reference)
constexpr int HH    = 1024;
constexpr int WW    = 1024;
constexpr int NPIX  = HH * WW;       // 1,048,576 pixels
constexpr int NB    = 16;            // batch replication factor
constexpr int PPT   = 8;             // pixels per thread
constexpr int BLOCK = 256;

// out(n,h,w,d) = mask ? sum_k bary(h,w,k) * verts0[faces(p2f(h,w),k), d] : 0
// replicated over n (reference gathers all batches from batch-0 face attrs,
// and batch-0's packing offset is 0, so raw face indices into batch-0 verts).
//
// Wire dtypes (evidence R0-R2): verts/bary = float32 (R1 bf16-read -> NaN),
// faces/p2f = int32 (harness converts integer inputs), out = FLOAT32
// (reference einsum output dtype; R2's bf16-packed writes decoded as f32 gave
// finite ~5.3 error = odd-index bf16 + mantissa noise vs ref).
__global__ __launch_bounds__(BLOCK) void uv_render_kernel(
    const float* __restrict__ verts,   // (16, 6890, 3) f32 — only batch 0 read
    const int*   __restrict__ faces,   // (13776, 3) int32
    const int*   __restrict__ p2f,     // (H, W) int32
    const float* __restrict__ bary,    // (H, W, 3) f32
    float*       __restrict__ out)     // (16, H, W, 3) f32
{
    const int  t  = blockIdx.x * blockDim.x + threadIdx.x;
    const long p0 = (long)t * PPT;                 // first pixel of this thread
    if (p0 >= NPIX) return;

    // ---- vector loads: 8 face ids (2x int4), 24 bary f32 (6x float4) ----
    const int4* pf4 = (const int4*)(p2f + p0);     // byte offset 32*t, 16B aligned
    const int4 f01 = pf4[0];
    const int4 f23 = pf4[1];
    const int fidx[PPT] = {f01.x, f01.y, f01.z, f01.w, f23.x, f23.y, f23.z, f23.w};

    const float4* b4 = (const float4*)(bary + p0 * 3); // byte offset 96*t, 16B aligned
    float b[PPT * 3];
    #pragma unroll
    for (int i = 0; i < 6; ++i) {
        const float4 v = b4[i];
        b[4 * i + 0] = v.x;
        b[4 * i + 1] = v.y;
        b[4 * i + 2] = v.z;
        b[4 * i + 3] = v.w;
    }

    // ---- per-pixel gather + dot (fp32) ----
    alignas(16) float res[PPT * 3];
    #pragma unroll
    for (int i = 0; i < PPT; ++i) {
        const int f = fidx[i];
        float o0 = 0.f, o1 = 0.f, o2 = 0.f;
        if (f >= 0) {
            const int v0 = faces[3 * f + 0];
            const int v1 = faces[3 * f + 1];
            const int v2 = faces[3 * f + 2];
            const float* a0 = verts + 3 * v0;  // batch-0 slice only (83 KB, cache-hot)
            const float* a1 = verts + 3 * v1;
            const float* a2 = verts + 3 * v2;
            const float w0 = b[3 * i + 0];
            const float w1 = b[3 * i + 1];
            const float w2 = b[3 * i + 2];
            o0 = w0 * a0[0] + w1 * a1[0] + w2 * a2[0];
            o1 = w0 * a0[1] + w1 * a1[1] + w2 * a2[1];
            o2 = w0 * a0[2] + w1 * a1[2] + w2 * a2[2];
        }
        res[3 * i + 0] = o0;
        res[3 * i + 1] = o1;
        res[3 * i + 2] = o2;
    }

    // ---- replicate-store: 16 batches x 96 bytes (6x dwordx4 each) ----
    const float4* r4 = (const float4*)res;
    const float4 r0 = r4[0], r1 = r4[1], r2 = r4[2];
    const float4 r3 = r4[3], r4v = r4[4], r5 = r4[5];
    #pragma unroll
    for (int n = 0; n < NB; ++n) {
        float4* dst = (float4*)(out + (size_t)n * (size_t)NPIX * 3 + p0 * 3);
        dst[0] = r0;
        dst[1] = r1;
        dst[2] = r2;
        dst[3] = r3;
        dst[4] = r4v;
        dst[5] = r5;
    }
}

extern "C" void kernel_launch(void* const* d_in, const int* in_sizes, int n_in,
                              void* d_out, int out_size, void* d_ws, size_t ws_size,
                              hipStream_t stream) {
    const float* verts = (const float*)d_in[0];   // (16, 6890, 3) f32
    const int*   faces = (const int*)d_in[1];     // (13776, 3) int32
    const int*   p2f   = (const int*)d_in[2];     // (1024, 1024) int32
    const float* bary  = (const float*)d_in[3];   // (1024, 1024, 3) f32
    float*       out   = (float*)d_out;           // (16, 1024, 1024, 3) f32

    const int threads = NPIX / PPT;           // 131072
    const int grid    = threads / BLOCK;      // 512
    uv_render_kernel<<<grid, BLOCK, 0, stream>>>(verts, faces, p2f, bary, out);
}

// Round 4
// 229.969 us; speedup vs baseline: 1.0673x; 1.0673x over previous
//
#include <hip/hip_runtime.h>
#include <hip/hip_bf16.h>

// Problem constants (from reference)
constexpr int HH    = 1024;
constexpr int WW    = 1024;
constexpr int NPIX  = HH * WW;        // 1,048,576 pixels
constexpr int NB    = 16;             // batch replication factor
constexpr int PPT   = 4;              // pixels per thread (phase 1)
constexpr int BLOCK = 256;
constexpr int MAPF4 = NPIX * 3 / 4;   // float4s per batch image = 786432

// Wire dtypes (evidence R0-R3): verts/bary f32, faces/p2f int32, out f32.
// out(n,h,w,d) is batch-invariant (reference gathers all batches from
// batch-0 face attrs; batch-0 packing offset is 0).
//
// Phase 1: compute the (H,W,3) map once, write into out batch 0.
// Grid 1024 blocks (4 blocks/CU, 16 waves/CU) to hide the gather chain.
__global__ __launch_bounds__(BLOCK) void uv_compute_map(
    const float* __restrict__ verts,   // (16, 6890, 3) f32 — only batch 0 read
    const int*   __restrict__ faces,   // (13776, 3) int32
    const int*   __restrict__ p2f,     // (H, W) int32
    const float* __restrict__ bary,    // (H, W, 3) f32
    float*       __restrict__ out)     // batch 0 slice: (H, W, 3) f32
{
    const int t  = blockIdx.x * blockDim.x + threadIdx.x;
    const int p0 = t * PPT;                        // first pixel of this thread
    if (p0 >= NPIX) return;

    // ---- vector loads: 4 face ids (int4), 12 bary f32 (3x float4) ----
    const int4 fi = *(const int4*)(p2f + p0);      // 16B aligned (16*t)
    const int fidx[PPT] = {fi.x, fi.y, fi.z, fi.w};

    const float4* b4 = (const float4*)(bary + (size_t)p0 * 3); // 48*t, aligned
    const float4 bv0 = b4[0], bv1 = b4[1], bv2 = b4[2];
    const float b[PPT * 3] = {bv0.x, bv0.y, bv0.z, bv0.w,
                              bv1.x, bv1.y, bv1.z, bv1.w,
                              bv2.x, bv2.y, bv2.z, bv2.w};

    // ---- per-pixel gather + dot (fp32); tables are L1/L2-resident ----
    alignas(16) float res[PPT * 3];
    #pragma unroll
    for (int i = 0; i < PPT; ++i) {
        const int f = fidx[i];
        float o0 = 0.f, o1 = 0.f, o2 = 0.f;
        if (f >= 0) {
            const int v0 = faces[3 * f + 0];
            const int v1 = faces[3 * f + 1];
            const int v2 = faces[3 * f + 2];
            const float* a0 = verts + 3 * v0;      // batch-0 slice (83 KB)
            const float* a1 = verts + 3 * v1;
            const float* a2 = verts + 3 * v2;
            const float w0 = b[3 * i + 0];
            const float w1 = b[3 * i + 1];
            const float w2 = b[3 * i + 2];
            o0 = w0 * a0[0] + w1 * a1[0] + w2 * a2[0];
            o1 = w0 * a0[1] + w1 * a1[1] + w2 * a2[1];
            o2 = w0 * a0[2] + w1 * a1[2] + w2 * a2[2];
        }
        res[3 * i + 0] = o0;
        res[3 * i + 1] = o1;
        res[3 * i + 2] = o2;
    }

    // ---- coalesced store: 48 B contiguous per thread (3x dwordx4) ----
    float4* dst = (float4*)(out + (size_t)p0 * 3);
    const float4* r4 = (const float4*)res;
    dst[0] = r4[0];
    dst[1] = r4[1];
    dst[2] = r4[2];
}

// Phase 2: replicate batch 0 -> batches 1..15. One float4 read (L2/LLC) +
// 15 fully-coalesced float4 stores per thread. Grid 3072 (12 blocks/CU).
__global__ __launch_bounds__(BLOCK) void uv_replicate(
    float* __restrict__ out)           // (16, H, W, 3) f32 as float4s
{
    const int tid = blockIdx.x * blockDim.x + threadIdx.x;
    if (tid >= MAPF4) return;
    const float4 v = ((const float4*)out)[tid];
    float4* o4 = (float4*)out;
    #pragma unroll
    for (int n = 1; n < NB; ++n)
        o4[(size_t)n * MAPF4 + tid] = v;
}

extern "C" void kernel_launch(void* const* d_in, const int* in_sizes, int n_in,
                              void* d_out, int out_size, void* d_ws, size_t ws_size,
                              hipStream_t stream) {
    const float* verts = (const float*)d_in[0];   // (16, 6890, 3) f32
    const int*   faces = (const int*)d_in[1];     // (13776, 3) int32
    const int*   p2f   = (const int*)d_in[2];     // (1024, 1024) int32
    const float* bary  = (const float*)d_in[3];   // (1024, 1024, 3) f32
    float*       out   = (float*)d_out;           // (16, 1024, 1024, 3) f32

    const int grid1 = NPIX / PPT / BLOCK;         // 1024
    uv_compute_map<<<grid1, BLOCK, 0, stream>>>(verts, faces, p2f, bary, out);

    const int grid2 = MAPF4 / BLOCK;              // 3072
    uv_replicate<<<grid2, BLOCK, 0, stream>>>(out);
}

// Round 6
// 227.133 us; speedup vs baseline: 1.0806x; 1.0125x over previous
//
#include <hip/hip_runtime.h>
#include <hip/hip_bf16.h>

// Problem constants (from reference)
constexpr int HH    = 1024;
constexpr int WW    = 1024;
constexpr int NPIX  = HH * WW;        // 1,048,576 pixels
constexpr int NB    = 16;             // batch replication factor
constexpr int PPT   = 4;              // pixels per thread (phase 1)
constexpr int BLOCK = 256;
constexpr int MAPF4 = NPIX * 3 / 4;   // float4s per batch image = 786432
constexpr int REPF4 = (NB - 1) * MAPF4; // float4s written by phase 2 = 11,796,480

// Native vector type — __builtin_nontemporal_store rejects HIP_vector_type.
typedef float vfloat4 __attribute__((ext_vector_type(4)));

// Wire dtypes (evidence R0-R3): verts/bary f32, faces/p2f int32, out f32.
// out(n,h,w,d) is batch-invariant (reference gathers all batches from
// batch-0 face attrs; batch-0 packing offset is 0).
//
// Phase 1: compute the (H,W,3) map once, write into out batch 0.
__global__ __launch_bounds__(BLOCK) void uv_compute_map(
    const float* __restrict__ verts,   // (16, 6890, 3) f32 — only batch 0 read
    const int*   __restrict__ faces,   // (13776, 3) int32
    const int*   __restrict__ p2f,     // (H, W) int32
    const float* __restrict__ bary,    // (H, W, 3) f32
    float*       __restrict__ out)     // batch 0 slice: (H, W, 3) f32
{
    const int t  = blockIdx.x * blockDim.x + threadIdx.x;
    const int p0 = t * PPT;                        // first pixel of this thread
    if (p0 >= NPIX) return;

    const int4 fi = *(const int4*)(p2f + p0);      // 16B aligned (16*t)
    const int fidx[PPT] = {fi.x, fi.y, fi.z, fi.w};

    const float4* b4 = (const float4*)(bary + (size_t)p0 * 3); // 48*t, aligned
    const float4 bv0 = b4[0], bv1 = b4[1], bv2 = b4[2];
    const float b[PPT * 3] = {bv0.x, bv0.y, bv0.z, bv0.w,
                              bv1.x, bv1.y, bv1.z, bv1.w,
                              bv2.x, bv2.y, bv2.z, bv2.w};

    alignas(16) float res[PPT * 3];
    #pragma unroll
    for (int i = 0; i < PPT; ++i) {
        const int f = fidx[i];
        float o0 = 0.f, o1 = 0.f, o2 = 0.f;
        if (f >= 0) {
            const int v0 = faces[3 * f + 0];
            const int v1 = faces[3 * f + 1];
            const int v2 = faces[3 * f + 2];
            const float* a0 = verts + 3 * v0;      // batch-0 slice (83 KB, hot)
            const float* a1 = verts + 3 * v1;
            const float* a2 = verts + 3 * v2;
            const float w0 = b[3 * i + 0];
            const float w1 = b[3 * i + 1];
            const float w2 = b[3 * i + 2];
            o0 = w0 * a0[0] + w1 * a1[0] + w2 * a2[0];
            o1 = w0 * a0[1] + w1 * a1[1] + w2 * a2[1];
            o2 = w0 * a0[2] + w1 * a1[2] + w2 * a2[2];
        }
        res[3 * i + 0] = o0;
        res[3 * i + 1] = o1;
        res[3 * i + 2] = o2;
    }

    float4* dst = (float4*)(out + (size_t)p0 * 3);
    const float4* r4 = (const float4*)res;
    dst[0] = r4[0];
    dst[1] = r4[1];
    dst[2] = r4[2];
}

// Phase 2: replicate batch 0 -> batches 1..15 with PURELY SEQUENTIAL stores
// (same address pattern as the 6.7 TB/s fillBuffer). One thread per output
// float4; src index = tid % MAPF4 (12.6 MB map, LLC-resident, 15x reuse).
// R4's version strode 12 MiB between a thread's stores — exact power-of-two
// channel/L2-set aliasing; this removes it.
__global__ __launch_bounds__(BLOCK) void uv_replicate(
    const vfloat4* __restrict__ map,   // out batch 0, read-only here
    vfloat4*       __restrict__ dst)   // out + MAPF4 (batches 1..15)
{
    const int tid = blockIdx.x * blockDim.x + threadIdx.x;
    if (tid >= REPF4) return;
    const int m = tid % MAPF4;                 // magic-mul, ~4 VALU ops
    const vfloat4 v = map[m];
    __builtin_nontemporal_store(v, dst + tid); // streaming store, never re-read
}

extern "C" void kernel_launch(void* const* d_in, const int* in_sizes, int n_in,
                              void* d_out, int out_size, void* d_ws, size_t ws_size,
                              hipStream_t stream) {
    const float* verts = (const float*)d_in[0];   // (16, 6890, 3) f32
    const int*   faces = (const int*)d_in[1];     // (13776, 3) int32
    const int*   p2f   = (const int*)d_in[2];     // (1024, 1024) int32
    const float* bary  = (const float*)d_in[3];   // (1024, 1024, 3) f32
    float*       out   = (float*)d_out;           // (16, 1024, 1024, 3) f32

    const int grid1 = NPIX / PPT / BLOCK;         // 1024
    uv_compute_map<<<grid1, BLOCK, 0, stream>>>(verts, faces, p2f, bary, out);

    const int grid2 = (REPF4 + BLOCK - 1) / BLOCK; // 46080
    uv_replicate<<<grid2, BLOCK, 0, stream>>>((const vfloat4*)out,
                                              (vfloat4*)out + MAPF4);
}